// Round 4
// baseline (151.691 us; speedup 1.0000x reference)
//
#include <hip/hip_runtime.h>

#define NROWS 8192
#define DDIM 256
#define MARGIN_F 0.2f
#define CSPLIT 32

typedef _Float16 half8 __attribute__((ext_vector_type(8)));
typedef float f32x4 __attribute__((ext_vector_type(4)));
typedef int i32x4 __attribute__((ext_vector_type(4)));

__device__ __forceinline__ void gld16(const void* g, void* l) {
  __builtin_amdgcn_global_load_lds(
      (const __attribute__((address_space(1))) void*)g,
      (__attribute__((address_space(3))) void*)l, 16, 0, 0);
}

// ---------------- kernel 1: split fp32 -> hi/lo fp16 in MFMA-tiled layout + sq ----------------
// Tiled layout: chunk (rg, kt) = 1024B at ((rg*8+kt)*512 halves): [g 0..3][r 0..15][8 halves]
// so lane l of a wave maps to offset l*16B with r=l&15, g=l>>4.
__global__ __launch_bounds__(256)
void prep_kernel(const float* __restrict__ E, _Float16* __restrict__ Eh,
                 _Float16* __restrict__ El, float* __restrict__ sq) {
  const int t = threadIdx.x;
  const int r = t >> 4;        // row within 16-row group
  const int cs = t & 15;       // 16-col segment
  const int rg = blockIdx.x;
  const int row = rg * 16 + r;
  const float* src = &E[row * DDIM + cs * 16];
  float s = 0.f;
  half8 H[2], L[2];
#pragma unroll
  for (int h = 0; h < 2; ++h) {
    const float4 f0 = *(const float4*)(src + h * 8);
    const float4 f1 = *(const float4*)(src + h * 8 + 4);
    const float v[8] = {f0.x, f0.y, f0.z, f0.w, f1.x, f1.y, f1.z, f1.w};
#pragma unroll
    for (int e = 0; e < 8; ++e) {
      s = fmaf(v[e], v[e], s);
      const _Float16 hi = (_Float16)v[e];
      H[h][e] = hi;
      L[h][e] = (_Float16)(v[e] - (float)hi);
    }
  }
  const int kt = cs >> 1;
  const int g0 = (cs & 1) * 2;
  const int base = (rg * 8 + kt) * 512;
  *(half8*)&Eh[base + g0 * 128 + r * 8] = H[0];
  *(half8*)&Eh[base + (g0 + 1) * 128 + r * 8] = H[1];
  *(half8*)&El[base + g0 * 128 + r * 8] = L[0];
  *(half8*)&El[base + (g0 + 1) * 128 + r * 8] = L[1];
#pragma unroll
  for (int o = 8; o > 0; o >>= 1) s += __shfl_down(s, o, 16);
  if (cs == 0) sq[row] = s;
}

// ---------------- kernel 2: split-fp16 MFMA dist-GEMM + mining, 256x256 tile ----------------
// 512 thr = 8 waves: wi = w>>1 (0..3, i-quadrant of 64), wj = w&1 (0..1, j-half of 128).
// acc[8 jf][4 fi] f32x4. LDS: 2 dbuf x 4 arrays (SiH,SiL,SjH,SjL) x 8192 halves = 128 KB.
__global__ __launch_bounds__(512, 2)
void mine_kernel(const _Float16* __restrict__ Eh, const _Float16* __restrict__ El,
                 const int* __restrict__ T, const float* __restrict__ sq,
                 float* __restrict__ pv, int* __restrict__ pi,
                 float* __restrict__ nv, int* __restrict__ ni) {
  __shared__ __align__(16) _Float16 S[2][4][8192];

  const int tid = threadIdx.x;
  const int lane = tid & 63;
  const int w = tid >> 6;
  const int wi = w >> 1, wj = w & 1;
  const int l15 = lane & 15, grp = lane >> 4;
  const int rowbase = blockIdx.y * 256;
  const int colbase = blockIdx.x * 256;

  // staging role: waves (arr, half) — wave w stages half `half` of array `arr`
  const int arr = w >> 1;              // 0:SiH 1:SiL 2:SjH 3:SjL
  const int shalf = w & 1;
  const _Float16* sA = (arr & 1) ? El : Eh;
  const int rgb = (((arr < 2) ? rowbase : colbase) >> 4) + shalf * 8;

  float sqi[4]; int ti[4];
#pragma unroll
  for (int fi = 0; fi < 4; ++fi) {
    const int i = rowbase + wi * 64 + fi * 16 + l15;
    sqi[fi] = sq[i];
    ti[fi] = T[i];
  }

  float bpv[4], bnv[4]; int bpi[4], bni[4];
#pragma unroll
  for (int fi = 0; fi < 4; ++fi) { bpv[fi] = -3e38f; bnv[fi] = 3e38f; bpi[fi] = 0; bni[fi] = 0; }

  f32x4 acc[8][4];
#pragma unroll
  for (int jf = 0; jf < 8; ++jf)
#pragma unroll
    for (int fi = 0; fi < 4; ++fi) acc[jf][fi] = (f32x4){0.f, 0.f, 0.f, 0.f};

  // prologue: stage kt=0 into buffer 0
#pragma unroll
  for (int t = 0; t < 8; ++t)
    gld16(sA + ((rgb + t) * 8 + 0) * 512 + lane * 8, &S[0][arr][(shalf * 8 + t) * 512]);
  __syncthreads();

  for (int kt = 0; kt < 8; ++kt) {
    const int cur = kt & 1;
    if (kt < 7) {   // prefetch next K-slice into the other buffer (issued before compute)
#pragma unroll
      for (int t = 0; t < 8; ++t)
        gld16(sA + ((rgb + t) * 8 + kt + 1) * 512 + lane * 8,
              &S[cur ^ 1][arr][(shalf * 8 + t) * 512]);
    }
#pragma unroll
    for (int jh = 0; jh < 2; ++jh) {
      half8 ajh[4], ajl[4];
#pragma unroll
      for (int jf = 0; jf < 4; ++jf) {
        const int rg = wj * 8 + jh * 4 + jf;
        ajh[jf] = *(const half8*)&S[cur][2][rg * 512 + lane * 8];
        ajl[jf] = *(const half8*)&S[cur][3][rg * 512 + lane * 8];
      }
#pragma unroll
      for (int fi = 0; fi < 4; ++fi) {
        const half8 bh = *(const half8*)&S[cur][0][(wi * 4 + fi) * 512 + lane * 8];
        const half8 bl = *(const half8*)&S[cur][1][(wi * 4 + fi) * 512 + lane * 8];
        __builtin_amdgcn_s_setprio(1);
#pragma unroll
        for (int jf = 0; jf < 4; ++jf)
          acc[jh * 4 + jf][fi] = __builtin_amdgcn_mfma_f32_16x16x32_f16(ajh[jf], bh, acc[jh * 4 + jf][fi], 0, 0, 0);
#pragma unroll
        for (int jf = 0; jf < 4; ++jf)
          acc[jh * 4 + jf][fi] = __builtin_amdgcn_mfma_f32_16x16x32_f16(ajl[jf], bh, acc[jh * 4 + jf][fi], 0, 0, 0);
#pragma unroll
        for (int jf = 0; jf < 4; ++jf)
          acc[jh * 4 + jf][fi] = __builtin_amdgcn_mfma_f32_16x16x32_f16(ajh[jf], bl, acc[jh * 4 + jf][fi], 0, 0, 0);
        __builtin_amdgcn_s_setprio(0);
      }
    }
    __syncthreads();
  }

  // epilogue: dist = sqi + sqj - 2*dot; online argmax(pos)/argmin(neg), first-index ties
#pragma unroll
  for (int jf = 0; jf < 8; ++jf) {
    const int jb = colbase + wj * 128 + jf * 16 + grp * 4;
    const f32x4 sqj = *(const f32x4*)&sq[jb];
    const i32x4 tj = *(const i32x4*)&T[jb];
#pragma unroll
    for (int fi = 0; fi < 4; ++fi) {
#pragma unroll
      for (int r = 0; r < 4; ++r) {
        const float dst = fmaf(-2.f, acc[jf][fi][r], sqi[fi] + sqj[r]);
        const int jidx = jb + r;
        if (ti[fi] == tj[r]) {
          if (dst > bpv[fi]) { bpv[fi] = dst; bpi[fi] = jidx; }
        } else {
          if (dst < bnv[fi]) { bnv[fi] = dst; bni[fi] = jidx; }
        }
      }
    }
  }

  // reduce across the 4 lane-groups (j sub-rows), index tie-break
#pragma unroll
  for (int fi = 0; fi < 4; ++fi) {
#pragma unroll
    for (int off = 16; off <= 32; off <<= 1) {
      const float ov = __shfl_xor(bpv[fi], off, 64);
      const int oi = __shfl_xor(bpi[fi], off, 64);
      if (ov > bpv[fi] || (ov == bpv[fi] && oi < bpi[fi])) { bpv[fi] = ov; bpi[fi] = oi; }
      const float on = __shfl_xor(bnv[fi], off, 64);
      const int oni = __shfl_xor(bni[fi], off, 64);
      if (on < bnv[fi] || (on == bnv[fi] && oni < bni[fi])) { bnv[fi] = on; bni[fi] = oni; }
    }
  }

  // combine the two j-waves via LDS, then write partials
  float4* scr = (float4*)&S[0][0][0];   // 256 entries
  if (wj == 1 && lane < 16) {
#pragma unroll
    for (int fi = 0; fi < 4; ++fi)
      scr[wi * 64 + fi * 16 + lane] =
          make_float4(bpv[fi], __int_as_float(bpi[fi]), bnv[fi], __int_as_float(bni[fi]));
  }
  __syncthreads();
  if (wj == 0 && lane < 16) {
#pragma unroll
    for (int fi = 0; fi < 4; ++fi) {
      const float4 o = scr[wi * 64 + fi * 16 + lane];
      const int oi = __float_as_int(o.y), oni = __float_as_int(o.w);
      if (o.x > bpv[fi] || (o.x == bpv[fi] && oi < bpi[fi])) { bpv[fi] = o.x; bpi[fi] = oi; }
      if (o.z < bnv[fi] || (o.z == bnv[fi] && oni < bni[fi])) { bnv[fi] = o.z; bni[fi] = oni; }
      const int row = rowbase + wi * 64 + fi * 16 + lane;
      const int oidx = row * CSPLIT + blockIdx.x;
      pv[oidx] = bpv[fi]; pi[oidx] = bpi[fi]; nv[oidx] = bnv[fi]; ni[oidx] = bni[fi];
    }
  }
}

// ---------------- kernel 3: combine splits, exact ap/an, losses, triplets ----------------
__global__ __launch_bounds__(256)
void finish_kernel(const float* __restrict__ E,
                   const float* __restrict__ pv, const int* __restrict__ pi,
                   const float* __restrict__ nv, const int* __restrict__ ni,
                   float* __restrict__ out, float* __restrict__ bl) {
  const int w = threadIdx.x >> 6, lane = threadIdx.x & 63;
  const int row = blockIdx.x * 4 + w;
  float Pv = -3e38f, Nv = 3e38f; int Pi = 0, Ni = 0;
#pragma unroll
  for (int s = 0; s < CSPLIT; ++s) {
    const float p = pv[row * CSPLIT + s]; const int px = pi[row * CSPLIT + s];
    if (p > Pv || (p == Pv && px < Pi)) { Pv = p; Pi = px; }
    const float n = nv[row * CSPLIT + s]; const int nx = ni[row * CSPLIT + s];
    if (n < Nv || (n == Nv && nx < Ni)) { Nv = n; Ni = nx; }
  }
  const float4 a = *(const float4*)&E[row * DDIM + lane * 4];
  const float4 p4 = *(const float4*)&E[Pi * DDIM + lane * 4];
  const float4 n4 = *(const float4*)&E[Ni * DDIM + lane * 4];
  float ap = (a.x - p4.x) * (a.x - p4.x) + (a.y - p4.y) * (a.y - p4.y)
           + (a.z - p4.z) * (a.z - p4.z) + (a.w - p4.w) * (a.w - p4.w);
  float an = (a.x - n4.x) * (a.x - n4.x) + (a.y - n4.y) * (a.y - n4.y)
           + (a.z - n4.z) * (a.z - n4.z) + (a.w - n4.w) * (a.w - n4.w);
#pragma unroll
  for (int o = 32; o > 0; o >>= 1) {
    ap += __shfl_down(ap, o, 64);
    an += __shfl_down(an, o, 64);
  }
  __shared__ float ls[4];
  if (lane == 0) {
    out[1 + row * 3 + 0] = (float)row;
    out[1 + row * 3 + 1] = (float)Pi;
    out[1 + row * 3 + 2] = (float)Ni;
    ls[w] = fmaxf(ap - an + MARGIN_F, 0.f);
  }
  __syncthreads();
  if (threadIdx.x == 0) bl[blockIdx.x] = (ls[0] + ls[1]) + (ls[2] + ls[3]);
}

// ---------------- kernel 4: deterministic mean ----------------
__global__ __launch_bounds__(256)
void sum_kernel(const float* __restrict__ bl, float* __restrict__ out) {
  __shared__ float s[256];
  float t = 0.f;
#pragma unroll
  for (int r = 0; r < (NROWS / 4) / 256; ++r) t += bl[threadIdx.x + r * 256];
  s[threadIdx.x] = t;
  __syncthreads();
  for (int o = 128; o > 0; o >>= 1) {
    if (threadIdx.x < o) s[threadIdx.x] += s[threadIdx.x + o];
    __syncthreads();
  }
  if (threadIdx.x == 0) out[0] = s[0] * (1.f / NROWS);
}

extern "C" void kernel_launch(void* const* d_in, const int* in_sizes, int n_in,
                              void* d_out, int out_size, void* d_ws, size_t ws_size,
                              hipStream_t stream) {
  const float* E = (const float*)d_in[0];
  const int* T = (const int*)d_in[1];
  float* out = (float*)d_out;

  // workspace carve-up (~12.05 MB)
  _Float16* Eh = (_Float16*)d_ws;                     // 4 MB
  _Float16* El = Eh + NROWS * DDIM;                   // 4 MB
  float* sq = (float*)(El + NROWS * DDIM);            // NROWS
  float* pv = sq + NROWS;                             // NROWS*CSPLIT (1 MB)
  int*   pi = (int*)(pv + NROWS * CSPLIT);
  float* nv = (float*)(pi + NROWS * CSPLIT);
  int*   ni = (int*)(nv + NROWS * CSPLIT);
  float* bl = (float*)(ni + NROWS * CSPLIT);          // NROWS/4

  prep_kernel<<<NROWS / 16, 256, 0, stream>>>(E, Eh, El, sq);
  mine_kernel<<<dim3(NROWS / 256, NROWS / 256), 512, 0, stream>>>(Eh, El, T, sq, pv, pi, nv, ni);
  finish_kernel<<<NROWS / 4, 256, 0, stream>>>(E, pv, pi, nv, ni, out, bl);
  sum_kernel<<<1, 256, 0, stream>>>(bl, out);
}